// Round 3
// baseline (796.895 us; speedup 1.0000x reference)
//
#include <hip/hip_runtime.h>
#include <hip/hip_bf16.h>

#define D 128

typedef __bf16 bf16x8 __attribute__((ext_vector_type(8)));
typedef __bf16 bf16x4 __attribute__((ext_vector_type(4)));
typedef __bf16 bf16x2 __attribute__((ext_vector_type(2)));
typedef float  f32x4  __attribute__((ext_vector_type(4)));
typedef float  f32x2  __attribute__((ext_vector_type(2)));

// ---------------------------------------------------------------------------
// Dtype probe: float tensors are either bf16 or fp32 — decide on device.
// Read 1024 32-bit words of inp. bits14:7 = bf16 exponent if bf16-packed
// (N(0,1) -> in [90,134] w.p. ~1); = uniform mantissa bits if fp32 (~17.6%).
// ---------------------------------------------------------------------------
__global__ void detect_kernel(const unsigned int* __restrict__ w, int* flag)
{
    __shared__ int cnt[256];
    int c = 0;
#pragma unroll
    for (int i = 0; i < 4; ++i) {
        unsigned int v = w[threadIdx.x * 4 + i];
        unsigned int e = (v >> 7) & 0xFF;
        if (e >= 90 && e <= 134) ++c;
    }
    cnt[threadIdx.x] = c;
    __syncthreads();
    for (int s = 128; s > 0; s >>= 1) {
        if (threadIdx.x < s) cnt[threadIdx.x] += cnt[threadIdx.x + s];
        __syncthreads();
    }
    if (threadIdx.x == 0) flag[0] = (cnt[0] > 614) ? 1 : 0;   // 1 = bf16
}

// dual-dtype load helpers (isbf is wave-uniform -> no divergence cost)
__device__ __forceinline__ bf16x8 ld8(const void* p, size_t elem, int isbf)
{
    if (isbf) return *(const bf16x8*)((const __bf16*)p + elem);
    const f32x4* f = (const f32x4*)((const float*)p + elem);
    f32x4 lo = f[0], hi = f[1];
    bf16x8 r;
    r[0] = (__bf16)lo[0]; r[1] = (__bf16)lo[1]; r[2] = (__bf16)lo[2]; r[3] = (__bf16)lo[3];
    r[4] = (__bf16)hi[0]; r[5] = (__bf16)hi[1]; r[6] = (__bf16)hi[2]; r[7] = (__bf16)hi[3];
    return r;
}
__device__ __forceinline__ f32x2 ld2f(const void* p, size_t elem, int isbf)
{
    f32x2 r;
    if (isbf) {
        bf16x2 v = *(const bf16x2*)((const __bf16*)p + elem);
        r[0] = (float)v[0]; r[1] = (float)v[1];
    } else {
        r = *(const f32x2*)((const float*)p + elem);
    }
    return r;
}
__device__ __forceinline__ float ldf(const void* p, size_t elem, int isbf)
{
    return isbf ? (float)((const __bf16*)p)[elem] : ((const float*)p)[elem];
}

// ---------------------------------------------------------------------------
// Phase 1: T[t][n][:] = inp[n][:] @ W_t^T  -> bf16 T in ws
// ---------------------------------------------------------------------------
__global__ __launch_bounds__(256) void gemm_kernel(
    const void* __restrict__ A,
    const void* __restrict__ W0, const void* __restrict__ W1,
    const void* __restrict__ W2, const void* __restrict__ W3,
    __bf16* __restrict__ T, int M, const int* __restrict__ flag)
{
    const int isbf = flag[0];
    const int t = blockIdx.y;
    const void* W = (t == 0) ? W0 : (t == 1) ? W1 : (t == 2) ? W2 : W3;
    const int wave = threadIdx.x >> 6;
    const int lane = threadIdx.x & 63;
    const int lrow = lane & 15;
    const int kgrp = lane >> 4;
    const int m_base = blockIdx.x * 128 + wave * 32;

    f32x4 acc[2][8];
#pragma unroll
    for (int i = 0; i < 2; ++i)
#pragma unroll
        for (int j = 0; j < 8; ++j)
            acc[i][j] = (f32x4){0.f, 0.f, 0.f, 0.f};

    int r0 = m_base + lrow;      if (r0 >= M) r0 = 0;   // clamped; stores guarded
    int r1 = m_base + 16 + lrow; if (r1 >= M) r1 = 0;

#pragma unroll
    for (int ks = 0; ks < 4; ++ks) {
        const int k0 = ks * 32 + kgrp * 8;
        bf16x8 a0 = ld8(A, (size_t)r0 * D + k0, isbf);
        bf16x8 a1 = ld8(A, (size_t)r1 * D + k0, isbf);
#pragma unroll
        for (int nj = 0; nj < 8; ++nj) {
            bf16x8 b = ld8(W, (size_t)(nj * 16 + lrow) * D + k0, isbf);
            acc[0][nj] = __builtin_amdgcn_mfma_f32_16x16x32_bf16(a0, b, acc[0][nj], 0, 0, 0);
            acc[1][nj] = __builtin_amdgcn_mfma_f32_16x16x32_bf16(a1, b, acc[1][nj], 0, 0, 0);
        }
    }

    // C/D layout: col = lane&15, row = (lane>>4)*4 + reg
    __bf16* Tt = T + (size_t)t * M * D;
#pragma unroll
    for (int mi = 0; mi < 2; ++mi) {
#pragma unroll
        for (int rg = 0; rg < 4; ++rg) {
            int row = m_base + mi * 16 + kgrp * 4 + rg;
            if (row < M) {
#pragma unroll
                for (int nj = 0; nj < 8; ++nj)
                    Tt[(size_t)row * D + nj * 16 + lrow] = (__bf16)acc[mi][nj][rg];
            }
        }
    }
}

// ---------------------------------------------------------------------------
// Phase 1b: G[t][n] = dot(inp[n], gate_t), fp32. One wave per node.
// ---------------------------------------------------------------------------
__global__ __launch_bounds__(256) void gate_kernel(
    const void* __restrict__ A,
    const void* __restrict__ g0, const void* __restrict__ g1,
    const void* __restrict__ g2, const void* __restrict__ g3,
    float* __restrict__ G, int M, const int* __restrict__ flag)
{
    const int isbf = flag[0];
    int node = blockIdx.x * 4 + (threadIdx.x >> 6);
    int lane = threadIdx.x & 63;
    if (node >= M) return;
    int d = lane * 2;
    f32x2 a  = ld2f(A, (size_t)node * D + d, isbf);
    f32x2 v0 = ld2f(g0, d, isbf);
    f32x2 v1 = ld2f(g1, d, isbf);
    f32x2 v2 = ld2f(g2, d, isbf);
    f32x2 v3 = ld2f(g3, d, isbf);
    float s0 = a[0] * v0[0] + a[1] * v0[1];
    float s1 = a[0] * v1[0] + a[1] * v1[1];
    float s2 = a[0] * v2[0] + a[1] * v2[1];
    float s3 = a[0] * v3[0] + a[1] * v3[1];
#pragma unroll
    for (int off = 32; off > 0; off >>= 1) {
        s0 += __shfl_down(s0, off);
        s1 += __shfl_down(s1, off);
        s2 += __shfl_down(s2, off);
        s3 += __shfl_down(s3, off);
    }
    if (lane == 0) {
        G[(size_t)0 * M + node] = s0;
        G[(size_t)1 * M + node] = s1;
        G[(size_t)2 * M + node] = s2;
        G[(size_t)3 * M + node] = s3;
    }
}

// ---------------------------------------------------------------------------
// Phase 2: per-edge gather + gate + fp32 atomic scatter-add (chunked targets)
// ---------------------------------------------------------------------------
__global__ __launch_bounds__(256) void edge_kernel(
    const __bf16* __restrict__ T, const float* __restrict__ G,
    const void* __restrict__ b_in, const void* __restrict__ b_out,
    const void* __restrict__ bg_in, const void* __restrict__ bg_out,
    const int* __restrict__ deprel, const int* __restrict__ deparc,
    const int* __restrict__ src, const int* __restrict__ tgt,
    float* __restrict__ accum, int M, int E, int lo, int hi,
    const int* __restrict__ flag)
{
    const int isbf = flag[0];
    int e = blockIdx.x * 4 + (threadIdx.x >> 6);
    if (e >= E) return;
    int g = tgt[e];
    if (g < lo || g >= hi) return;   // other chunk (wave-uniform)
    int lane = threadIdx.x & 63;
    int t = deparc[e];
    int r = deprel[e];
    int s = src[e];

    float gpre = G[(size_t)t * M + s];
    float bgate = 0.f;
    const void* brow = nullptr;
    if (t == 0)      { brow = b_in;  bgate = ldf(bg_in, r, isbf); }
    else if (t == 1) { brow = b_out; bgate = ldf(bg_out, r, isbf); }
    float gate = 1.f / (1.f + __expf(-(gpre + bgate)));

    int d = lane * 2;
    bf16x2 tv = *(const bf16x2*)(T + ((size_t)t * M + s) * D + d);
    float m0 = (float)tv[0], m1 = (float)tv[1];
    if (brow) {
        f32x2 bv = ld2f(brow, (size_t)r * D + d, isbf);
        m0 += bv[0];
        m1 += bv[1];
    }
    float* dst = accum + (size_t)(g - lo) * D + d;
    unsafeAtomicAdd(dst,     m0 * gate);
    unsafeAtomicAdd(dst + 1, m1 * gate);
}

// ---------------------------------------------------------------------------
// Phase 3: fp32 accum chunk -> output chunk (bf16 or fp32 per flag)
// ---------------------------------------------------------------------------
__global__ __launch_bounds__(256) void convert_kernel(
    const f32x4* __restrict__ a, void* __restrict__ out, size_t elem0, int n4,
    const int* __restrict__ flag)
{
    const int isbf = flag[0];
    int i = blockIdx.x * blockDim.x + threadIdx.x;
    if (i >= n4) return;
    f32x4 v = a[i];
    if (isbf) {
        bf16x4 w;
        w[0] = (__bf16)v[0]; w[1] = (__bf16)v[1];
        w[2] = (__bf16)v[2]; w[3] = (__bf16)v[3];
        ((bf16x4*)((__bf16*)out + elem0))[i] = w;
    } else {
        ((f32x4*)((float*)out + elem0))[i] = v;
    }
}

// Diagnostic sentinel if ws can't fit the layout.
__global__ void sentinel_kernel(__bf16* o, int n)
{
    int i = blockIdx.x * blockDim.x + threadIdx.x;
    if (i < n) o[i] = (__bf16)12345.0f;
}

extern "C" void kernel_launch(void* const* d_in, const int* in_sizes, int n_in,
                              void* d_out, int out_size, void* d_ws, size_t ws_size,
                              hipStream_t stream)
{
    const void* inp       = d_in[0];
    const int*  deprel    = (const int*)d_in[1];
    const int*  deparc    = (const int*)d_in[2];
    const int*  eidx      = (const int*)d_in[3];
    const void* V_in      = d_in[4];
    const void* b_in      = d_in[5];
    const void* V_in_g    = d_in[6];
    const void* b_in_g    = d_in[7];
    const void* V_out     = d_in[8];
    const void* b_out     = d_in[9];
    const void* V_out_g   = d_in[10];
    const void* b_out_g   = d_in[11];
    const void* W_self    = d_in[12];
    const void* W_self_g  = d_in[13];
    const void* W_norel   = d_in[14];
    const void* W_norel_g = d_in[15];

    const int M = in_sizes[0] / D;   // 100000
    const int E = in_sizes[1];       // 600000
    const int* src = eidx;
    const int* tgt = eidx + E;

    // ws: flags(256B) | T bf16 4*M*D | G f32 4*M | accum f32 chunk
    const size_t f_bytes = 256;
    const size_t t_bytes = (size_t)4 * M * D * sizeof(__bf16);
    const size_t g_bytes = (size_t)4 * M * sizeof(float);
    const size_t base = f_bytes + t_bytes + g_bytes;

    int n_chunks = -1, chunk_nodes = 0;
    for (int n = 1; n <= 64; ++n) {
        int cn = (M + n - 1) / n;
        if (base + (size_t)cn * D * sizeof(float) <= ws_size) {
            n_chunks = n; chunk_nodes = cn; break;
        }
    }
    if (n_chunks < 0) {
        sentinel_kernel<<<(out_size + 255) / 256, 256, 0, stream>>>(
            (__bf16*)d_out, out_size);
        return;
    }

    int*    flag  = (int*)d_ws;
    __bf16* Tbuf  = (__bf16*)((char*)d_ws + f_bytes);
    float*  Gbuf  = (float*)((char*)d_ws + f_bytes + t_bytes);
    float*  accum = (float*)((char*)d_ws + base);

    detect_kernel<<<1, 256, 0, stream>>>((const unsigned int*)inp, flag);

    dim3 ggrid((M + 127) / 128, 4);
    gemm_kernel<<<ggrid, 256, 0, stream>>>(inp, V_in, V_out, W_self, W_norel,
                                           Tbuf, M, flag);
    gate_kernel<<<(M + 3) / 4, 256, 0, stream>>>(inp, V_in_g, V_out_g, W_self_g,
                                                 W_norel_g, Gbuf, M, flag);

    for (int c = 0; c < n_chunks; ++c) {
        int lo = c * chunk_nodes;
        int hi = lo + chunk_nodes; if (hi > M) hi = M;
        int nn = hi - lo;
        hipMemsetAsync(accum, 0, (size_t)nn * D * sizeof(float), stream);
        edge_kernel<<<(E + 3) / 4, 256, 0, stream>>>(Tbuf, Gbuf, b_in, b_out,
                                                     b_in_g, b_out_g,
                                                     deprel, deparc, src, tgt,
                                                     accum, M, E, lo, hi, flag);
        int n4 = nn * D / 4;
        convert_kernel<<<(n4 + 255) / 256, 256, 0, stream>>>(
            (const f32x4*)accum, d_out, (size_t)lo * D, n4, flag);
    }
}

// Round 4
// 424.014 us; speedup vs baseline: 1.8794x; 1.8794x over previous
//
#include <hip/hip_runtime.h>
#include <hip/hip_bf16.h>

#define D 128

typedef __bf16 bf16x8 __attribute__((ext_vector_type(8)));
typedef __bf16 bf16x4 __attribute__((ext_vector_type(4)));
typedef __bf16 bf16x2 __attribute__((ext_vector_type(2)));
typedef float  f32x4  __attribute__((ext_vector_type(4)));
typedef float  f32x2  __attribute__((ext_vector_type(2)));

// ---------------------------------------------------------------------------
// Dtype probe (unchanged, verified working in R3): 1 = bf16-packed, 0 = fp32.
// ---------------------------------------------------------------------------
__global__ void detect_kernel(const unsigned int* __restrict__ w, int* flag)
{
    __shared__ int cnt[256];
    int c = 0;
#pragma unroll
    for (int i = 0; i < 4; ++i) {
        unsigned int v = w[threadIdx.x * 4 + i];
        unsigned int e = (v >> 7) & 0xFF;
        if (e >= 90 && e <= 134) ++c;
    }
    cnt[threadIdx.x] = c;
    __syncthreads();
    for (int s = 128; s > 0; s >>= 1) {
        if (threadIdx.x < s) cnt[threadIdx.x] += cnt[threadIdx.x + s];
        __syncthreads();
    }
    if (threadIdx.x == 0) flag[0] = (cnt[0] > 614) ? 1 : 0;
}

__device__ __forceinline__ bf16x8 ld8(const void* p, size_t elem, int isbf)
{
    if (isbf) return *(const bf16x8*)((const __bf16*)p + elem);
    const f32x4* f = (const f32x4*)((const float*)p + elem);
    f32x4 lo = f[0], hi = f[1];
    bf16x8 r;
    r[0] = (__bf16)lo[0]; r[1] = (__bf16)lo[1]; r[2] = (__bf16)lo[2]; r[3] = (__bf16)lo[3];
    r[4] = (__bf16)hi[0]; r[5] = (__bf16)hi[1]; r[6] = (__bf16)hi[2]; r[7] = (__bf16)hi[3];
    return r;
}
__device__ __forceinline__ f32x2 ld2f(const void* p, size_t elem, int isbf)
{
    f32x2 r;
    if (isbf) {
        bf16x2 v = *(const bf16x2*)((const __bf16*)p + elem);
        r[0] = (float)v[0]; r[1] = (float)v[1];
    } else {
        r = *(const f32x2*)((const float*)p + elem);
    }
    return r;
}
__device__ __forceinline__ float ldf(const void* p, size_t elem, int isbf)
{
    return isbf ? (float)((const __bf16*)p)[elem] : ((const float*)p)[elem];
}

// ---------------------------------------------------------------------------
// Phase 1: T[t][n][:] = inp[n][:] @ W_t^T  -> bf16 T in ws  (verified R3)
// ---------------------------------------------------------------------------
__global__ __launch_bounds__(256) void gemm_kernel(
    const void* __restrict__ A,
    const void* __restrict__ W0, const void* __restrict__ W1,
    const void* __restrict__ W2, const void* __restrict__ W3,
    __bf16* __restrict__ T, int M, const int* __restrict__ flag)
{
    const int isbf = flag[0];
    const int t = blockIdx.y;
    const void* W = (t == 0) ? W0 : (t == 1) ? W1 : (t == 2) ? W2 : W3;
    const int wave = threadIdx.x >> 6;
    const int lane = threadIdx.x & 63;
    const int lrow = lane & 15;
    const int kgrp = lane >> 4;
    const int m_base = blockIdx.x * 128 + wave * 32;

    f32x4 acc[2][8];
#pragma unroll
    for (int i = 0; i < 2; ++i)
#pragma unroll
        for (int j = 0; j < 8; ++j)
            acc[i][j] = (f32x4){0.f, 0.f, 0.f, 0.f};

    int r0 = m_base + lrow;      if (r0 >= M) r0 = 0;
    int r1 = m_base + 16 + lrow; if (r1 >= M) r1 = 0;

#pragma unroll
    for (int ks = 0; ks < 4; ++ks) {
        const int k0 = ks * 32 + kgrp * 8;
        bf16x8 a0 = ld8(A, (size_t)r0 * D + k0, isbf);
        bf16x8 a1 = ld8(A, (size_t)r1 * D + k0, isbf);
#pragma unroll
        for (int nj = 0; nj < 8; ++nj) {
            bf16x8 b = ld8(W, (size_t)(nj * 16 + lrow) * D + k0, isbf);
            acc[0][nj] = __builtin_amdgcn_mfma_f32_16x16x32_bf16(a0, b, acc[0][nj], 0, 0, 0);
            acc[1][nj] = __builtin_amdgcn_mfma_f32_16x16x32_bf16(a1, b, acc[1][nj], 0, 0, 0);
        }
    }

    __bf16* Tt = T + (size_t)t * M * D;
#pragma unroll
    for (int mi = 0; mi < 2; ++mi) {
#pragma unroll
        for (int rg = 0; rg < 4; ++rg) {
            int row = m_base + mi * 16 + kgrp * 4 + rg;
            if (row < M) {
#pragma unroll
                for (int nj = 0; nj < 8; ++nj)
                    Tt[(size_t)row * D + nj * 16 + lrow] = (__bf16)acc[mi][nj][rg];
            }
        }
    }
}

// ---------------------------------------------------------------------------
// Phase 1b: G[t][n] = dot(inp[n], gate_t), fp32. One wave per node.
// ---------------------------------------------------------------------------
__global__ __launch_bounds__(256) void gate_kernel(
    const void* __restrict__ A,
    const void* __restrict__ g0, const void* __restrict__ g1,
    const void* __restrict__ g2, const void* __restrict__ g3,
    float* __restrict__ G, int M, const int* __restrict__ flag)
{
    const int isbf = flag[0];
    int node = blockIdx.x * 4 + (threadIdx.x >> 6);
    int lane = threadIdx.x & 63;
    if (node >= M) return;
    int d = lane * 2;
    f32x2 a  = ld2f(A, (size_t)node * D + d, isbf);
    f32x2 v0 = ld2f(g0, d, isbf);
    f32x2 v1 = ld2f(g1, d, isbf);
    f32x2 v2 = ld2f(g2, d, isbf);
    f32x2 v3 = ld2f(g3, d, isbf);
    float s0 = a[0] * v0[0] + a[1] * v0[1];
    float s1 = a[0] * v1[0] + a[1] * v1[1];
    float s2 = a[0] * v2[0] + a[1] * v2[1];
    float s3 = a[0] * v3[0] + a[1] * v3[1];
#pragma unroll
    for (int off = 32; off > 0; off >>= 1) {
        s0 += __shfl_down(s0, off);
        s1 += __shfl_down(s1, off);
        s2 += __shfl_down(s2, off);
        s3 += __shfl_down(s3, off);
    }
    if (lane == 0) {
        G[(size_t)0 * M + node] = s0;
        G[(size_t)1 * M + node] = s1;
        G[(size_t)2 * M + node] = s2;
        G[(size_t)3 * M + node] = s3;
    }
}

// ---------------------------------------------------------------------------
// CSR build: histogram -> scan -> scatter (counting sort by target node)
// ---------------------------------------------------------------------------
__global__ __launch_bounds__(256) void hist_kernel(
    const int* __restrict__ tgt, int* __restrict__ counts, int E)
{
    int e = blockIdx.x * 256 + threadIdx.x;
    if (e < E) atomicAdd(&counts[tgt[e]], 1);
}

// scan1: per-block exclusive scan of 1024 counts; write block total.
__global__ __launch_bounds__(256) void scan1_kernel(
    const int* __restrict__ counts, int* __restrict__ rowptr,
    int* __restrict__ bsum, int M)
{
    __shared__ int sh[256];
    int base = blockIdx.x * 1024 + threadIdx.x * 4;
    int v[4];
#pragma unroll
    for (int k = 0; k < 4; ++k)
        v[k] = (base + k < M) ? counts[base + k] : 0;
    int tot = v[0] + v[1] + v[2] + v[3];
    sh[threadIdx.x] = tot;
    __syncthreads();
    // Hillis-Steele inclusive over 256
    for (int off = 1; off < 256; off <<= 1) {
        int t = (threadIdx.x >= off) ? sh[threadIdx.x - off] : 0;
        __syncthreads();
        sh[threadIdx.x] += t;
        __syncthreads();
    }
    int excl = sh[threadIdx.x] - tot;   // exclusive prefix of this thread
    int run = excl;
#pragma unroll
    for (int k = 0; k < 4; ++k) {
        if (base + k < M) rowptr[base + k] = run;
        run += v[k];
    }
    if (threadIdx.x == 255) bsum[blockIdx.x] = sh[255];
}

// scan2: single block scans block sums (NB <= 1024 via 256 threads x 4)
__global__ __launch_bounds__(256) void scan2_kernel(
    int* __restrict__ bsum, int* __restrict__ boff, int NB)
{
    __shared__ int sh[256];
    int base = threadIdx.x * 4;
    int v[4];
#pragma unroll
    for (int k = 0; k < 4; ++k)
        v[k] = (base + k < NB) ? bsum[base + k] : 0;
    int tot = v[0] + v[1] + v[2] + v[3];
    sh[threadIdx.x] = tot;
    __syncthreads();
    for (int off = 1; off < 256; off <<= 1) {
        int t = (threadIdx.x >= off) ? sh[threadIdx.x - off] : 0;
        __syncthreads();
        sh[threadIdx.x] += t;
        __syncthreads();
    }
    int run = sh[threadIdx.x] - tot;
#pragma unroll
    for (int k = 0; k < 4; ++k) {
        if (base + k < NB) boff[base + k] = run;
        run += v[k];
    }
}

// scan3: add block offsets; produce cursor copy; set rowptr[M]=E.
__global__ __launch_bounds__(256) void scan3_kernel(
    int* __restrict__ rowptr, int* __restrict__ cursor,
    const int* __restrict__ boff, int M, int E)
{
    int b = blockIdx.x;
    int base = b * 1024 + threadIdx.x * 4;
    int o = boff[b];
#pragma unroll
    for (int k = 0; k < 4; ++k) {
        int i = base + k;
        if (i < M) {
            int r = rowptr[i] + o;
            rowptr[i] = r;
            cursor[i] = r;
        }
    }
    if (b == 0 && threadIdx.x == 0) rowptr[M] = E;
}

// scatter edges into CSR order; record = {src, (rel<<2)|arc}
__global__ __launch_bounds__(256) void scatter_kernel(
    const int* __restrict__ deprel, const int* __restrict__ deparc,
    const int* __restrict__ src, const int* __restrict__ tgt,
    int* __restrict__ cursor, int2* __restrict__ recs, int E)
{
    int e = blockIdx.x * 256 + threadIdx.x;
    if (e >= E) return;
    int g = tgt[e];
    int pos = atomicAdd(&cursor[g], 1);
    recs[pos] = make_int2(src[e], (deprel[e] << 2) | deparc[e]);
}

// ---------------------------------------------------------------------------
// Phase 2 (new): atomic-free gather. One wave per target node.
// Cooperative 64-edge record prefetch; per-edge gate computed lane-parallel;
// T-row read 256B coalesced; accumulate 2 fp32/lane; write d_out directly.
// ---------------------------------------------------------------------------
__global__ __launch_bounds__(256) void gather_kernel(
    const __bf16* __restrict__ T, const float* __restrict__ G,
    const void* __restrict__ b_in, const void* __restrict__ b_out,
    const void* __restrict__ bg_in, const void* __restrict__ bg_out,
    const int* __restrict__ rowptr, const int2* __restrict__ recs,
    void* __restrict__ out, int M, const int* __restrict__ flag)
{
    const int isbf = flag[0];
    int g = blockIdx.x * 4 + (threadIdx.x >> 6);
    if (g >= M) return;
    int lane = threadIdx.x & 63;
    int beg = rowptr[g], end = rowptr[g + 1];

    float a0 = 0.f, a1 = 0.f;
    for (int base = beg; base < end; base += 64) {
        int n = end - base; if (n > 64) n = 64;
        int2 rec = (lane < n) ? recs[base + lane] : make_int2(0, 0);
        int t = rec.y & 3, r = rec.y >> 2;
        // gate pre-activation + relation gate bias, one edge per lane
        float gpre = G[(size_t)t * M + rec.x];
        float bg = 0.f;
        if (t == 0)      bg = ldf(bg_in, r, isbf);
        else if (t == 1) bg = ldf(bg_out, r, isbf);
        float gate = 1.f / (1.f + __expf(-(gpre + bg)));

        for (int j = 0; j < n; ++j) {
            int sj = __shfl(rec.x, j);
            int mj = __shfl(rec.y, j);
            float gj = __shfl(gate, j);
            int tj = mj & 3, rj = mj >> 2;
            int d = lane * 2;
            bf16x2 tv = *(const bf16x2*)(T + ((size_t)tj * M + sj) * D + d);
            float m0 = (float)tv[0], m1 = (float)tv[1];
            if (tj == 0) {
                f32x2 bv = ld2f(b_in, (size_t)rj * D + d, isbf);
                m0 += bv[0]; m1 += bv[1];
            } else if (tj == 1) {
                f32x2 bv = ld2f(b_out, (size_t)rj * D + d, isbf);
                m0 += bv[0]; m1 += bv[1];
            }
            a0 += m0 * gj;
            a1 += m1 * gj;
        }
    }

    int d = lane * 2;
    if (isbf) {
        bf16x2 w; w[0] = (__bf16)a0; w[1] = (__bf16)a1;
        *(bf16x2*)((__bf16*)out + (size_t)g * D + d) = w;
    } else {
        f32x2 w; w[0] = a0; w[1] = a1;
        *(f32x2*)((float*)out + (size_t)g * D + d) = w;
    }
}

// Diagnostic sentinel if ws can't fit the layout (should never trigger).
__global__ void sentinel_kernel(__bf16* o, int n)
{
    int i = blockIdx.x * blockDim.x + threadIdx.x;
    if (i < n) o[i] = (__bf16)12345.0f;
}

static inline size_t align256(size_t x) { return (x + 255) & ~(size_t)255; }

extern "C" void kernel_launch(void* const* d_in, const int* in_sizes, int n_in,
                              void* d_out, int out_size, void* d_ws, size_t ws_size,
                              hipStream_t stream)
{
    const void* inp       = d_in[0];
    const int*  deprel    = (const int*)d_in[1];
    const int*  deparc    = (const int*)d_in[2];
    const int*  eidx      = (const int*)d_in[3];
    const void* V_in      = d_in[4];
    const void* b_in      = d_in[5];
    const void* V_in_g    = d_in[6];
    const void* b_in_g    = d_in[7];
    const void* V_out     = d_in[8];
    const void* b_out     = d_in[9];
    const void* V_out_g   = d_in[10];
    const void* b_out_g   = d_in[11];
    const void* W_self    = d_in[12];
    const void* W_self_g  = d_in[13];
    const void* W_norel   = d_in[14];
    const void* W_norel_g = d_in[15];

    const int M = in_sizes[0] / D;   // 100000
    const int E = in_sizes[1];       // 600000
    const int* src = eidx;
    const int* tgt = eidx + E;
    const int NB = (M + 1023) / 1024;   // scan blocks (<=1024 supported)

    // ws layout
    size_t off = 0;
    size_t o_flag   = off; off = align256(off + sizeof(int));
    size_t o_T      = off; off = align256(off + (size_t)4 * M * D * sizeof(__bf16));
    size_t o_G      = off; off = align256(off + (size_t)4 * M * sizeof(float));
    size_t o_counts = off; off = align256(off + (size_t)M * sizeof(int));
    size_t o_rowptr = off; off = align256(off + (size_t)(M + 1) * sizeof(int));
    size_t o_cursor = off; off = align256(off + (size_t)M * sizeof(int));
    size_t o_bsum   = off; off = align256(off + (size_t)NB * sizeof(int));
    size_t o_boff   = off; off = align256(off + (size_t)NB * sizeof(int));
    size_t o_recs   = off; off = align256(off + (size_t)E * sizeof(int2));

    if (off > ws_size) {
        sentinel_kernel<<<(out_size + 255) / 256, 256, 0, stream>>>(
            (__bf16*)d_out, out_size);
        return;
    }

    int*    flag   = (int*)((char*)d_ws + o_flag);
    __bf16* Tbuf   = (__bf16*)((char*)d_ws + o_T);
    float*  Gbuf   = (float*)((char*)d_ws + o_G);
    int*    counts = (int*)((char*)d_ws + o_counts);
    int*    rowptr = (int*)((char*)d_ws + o_rowptr);
    int*    cursor = (int*)((char*)d_ws + o_cursor);
    int*    bsum   = (int*)((char*)d_ws + o_bsum);
    int*    boff   = (int*)((char*)d_ws + o_boff);
    int2*   recs   = (int2*)((char*)d_ws + o_recs);

    detect_kernel<<<1, 256, 0, stream>>>((const unsigned int*)inp, flag);

    // CSR build (independent of gemm/gate)
    hipMemsetAsync(counts, 0, (size_t)M * sizeof(int), stream);
    hist_kernel<<<(E + 255) / 256, 256, 0, stream>>>(tgt, counts, E);
    scan1_kernel<<<NB, 256, 0, stream>>>(counts, rowptr, bsum, M);
    scan2_kernel<<<1, 256, 0, stream>>>(bsum, boff, NB);
    scan3_kernel<<<NB, 256, 0, stream>>>(rowptr, cursor, boff, M, E);
    scatter_kernel<<<(E + 255) / 256, 256, 0, stream>>>(deprel, deparc, src, tgt,
                                                        cursor, recs, E);

    // node transforms + gates
    dim3 ggrid((M + 127) / 128, 4);
    gemm_kernel<<<ggrid, 256, 0, stream>>>(inp, V_in, V_out, W_self, W_norel,
                                           Tbuf, M, flag);
    gate_kernel<<<(M + 3) / 4, 256, 0, stream>>>(inp, V_in_g, V_out_g, W_self_g,
                                                 W_norel_g, Gbuf, M, flag);

    // atomic-free scatter-add as per-node gather, writes d_out directly
    gather_kernel<<<(M + 3) / 4, 256, 0, stream>>>(Tbuf, Gbuf, b_in, b_out,
                                                   b_in_g, b_out_g,
                                                   rowptr, recs, d_out, M, flag);
}